// Round 8
// baseline (238.601 us; speedup 1.0000x reference)
//
#include <hip/hip_runtime.h>

#define B_ 4
#define L_ 4096
#define D_ 1024
#define N_ 64

typedef _Float16 f16;
typedef __attribute__((ext_vector_type(8))) _Float16 half8;
typedef __attribute__((ext_vector_type(4))) float f32x4;

__device__ __forceinline__ float softplus_f(float x) {
    return fmaxf(x, 0.0f) + log1pf(__expf(-fabsf(x)));
}

__device__ __forceinline__ float tanh_f(float x) {
    float xc = fminf(fmaxf(x, -15.0f), 15.0f);
    float e = __expf(2.0f * xc);
    return (e - 1.0f) / (e + 1.0f);
}

__device__ __forceinline__ void bar_raw() {
    asm volatile("" ::: "memory");
    __builtin_amdgcn_s_barrier();
    asm volatile("" ::: "memory");
}

// ---------------------------------------------------------------------------
// Prep: WT [192][1024] f16 (rows 0-127 = Wp cols, 128-191 = Ws cols);
// WoT [1024][64] f16.  Coalesced reads (lane-consecutive column).
// ---------------------------------------------------------------------------
__global__ __launch_bounds__(256) void k_prepw(
    const float* __restrict__ Wp, const float* __restrict__ Ws,
    const float* __restrict__ Wo, f16* __restrict__ WT, f16* __restrict__ WoT)
{
    int gid = blockIdx.x * 256 + threadIdx.x;
    if (gid < 16384) {                        // Wp: [1024][128]
        int c = gid & 127, kg = gid >> 7;
        f16 h[8];
        #pragma unroll
        for (int j = 0; j < 8; j++)
            h[j] = (f16)Wp[(size_t)(kg * 8 + j) * 128 + c];
        *(uint4*)&WT[(size_t)c * 1024 + kg * 8] = *(uint4*)h;
    } else if (gid < 24576) {                 // Ws: [1024][64]
        int idx = gid - 16384;
        int c = idx & 63, kg = idx >> 6;
        f16 h[8];
        #pragma unroll
        for (int j = 0; j < 8; j++)
            h[j] = (f16)Ws[(size_t)(kg * 8 + j) * 64 + c];
        *(uint4*)&WT[(size_t)(128 + c) * 1024 + kg * 8] = *(uint4*)h;
    } else {                                  // Wo -> WoT [1024][64]
        int idx = gid - 24576;
        int d = idx & 1023, ng = idx >> 10;
        f16 h[8];
        #pragma unroll
        for (int j = 0; j < 8; j++)
            h[j] = (f16)Wo[(size_t)(ng * 8 + j) * D_ + d];
        *(uint4*)&WoT[(size_t)d * 64 + ng * 8] = *(uint4*)h;
    }
}

// ---------------------------------------------------------------------------
// Fused frontend v9: 32 tok/block, 512 thr / 8 waves, grid 512 = 2 blocks/CU.
// Register-diet rework of v8 (v8 spilled ~23MB scratch: rW dbuf + 2 n-frags
// blew the 128-VGPR cap):
//   - conv weights in LDS (cwS, staged once)   -> frees 40 VGPR
//   - 1 n-frag/wave (acc 12 VGPR), x-prefetch 4 rows/thread (32 VGPR dbuf)
//   - WT chunk [192][64] reg-staged (24 VGPR dbuf) -> ds_write, dbuf LDS
//   - row stride 136B (34 dw = 2 mod 32): padding replaces XOR swizzle,
//     frag reads <=4-way banked (v8's XOR pattern was ~8-way on A-reads)
//   - no vmcnt(0) in the loop: CONV waits its own x regs (counted), DSWT
//     waits only the 3 WT loads (x prefetch stays in flight across chunk)
// Waves: wc = w&3 (48-col group), wn = w>>2 (16-tok half); 6 MFMA/chunk/wave.
// LDS 81408B: wt0/wt1 26112 each, chb/xhb 4352 each, cwS 20480; sE aliases.
// ---------------------------------------------------------------------------
#define WST 136
__global__ __launch_bounds__(512, 4) void k_frontend(
    const float* __restrict__ x, const float* __restrict__ conv_w,
    const float* __restrict__ conv_b, const f16* __restrict__ WT,
    const float* __restrict__ bp, const float* __restrict__ bs,
    const float* __restrict__ dt_log,
    f16* __restrict__ zT, f16* __restrict__ cT)
{
    __shared__ __align__(16) char smem[81408];
    char* wt0 = smem;                     // [192][WST]
    char* wt1 = smem + 26112;             // [192][WST]
    char* chb = smem + 52224;             // [32][WST] conv f16
    char* xhb = smem + 56576;             // [32][WST] raw x f16
    float* cwS = (float*)(smem + 60928);  // [5][1024] f32
    float* sE  = (float*)smem;            // epilogue alias [3][32][68] f32

    const int tid = threadIdx.x;
    const int w = tid >> 6, lane = tid & 63;
    const int r = lane & 15, q = lane >> 4;
    const int wc = w & 3, wn = w >> 2;
    const int T0 = blockIdx.x * 32;
    const int bb = T0 >> 12, l0 = T0 & (L_ - 1);
    const int cbase = wc * 48;
    const int ct = tid >> 4;              // conv token 0..31
    const int cd = (tid & 15) * 4;        // conv dim group (4 dims)

    f32x4 acc[3] = {};
    f32x4 rXa[4], rXb[4];
    uint4 rSa[3], rSb[3];

    // WT chunk stage regs: 1536 slots of 16B; slot = tid + 512*s
    #define WLOAD(RS, c) { _Pragma("unroll") \
        for (int s = 0; s < 3; s++) { \
            int slot = tid + 512 * s; \
            RS[s] = *(const uint4*)&WT[(size_t)(slot >> 3) * 1024 + (c) * 64 + (slot & 7) * 8]; \
        } }
    #define DSWT(BUF, RS) { _Pragma("unroll") \
        for (int s = 0; s < 3; s++) { \
            int slot = tid + 512 * s; \
            *(uint4*)((BUF) + (slot >> 3) * WST + (slot & 7) * 16) = RS[s]; \
        } }
    // x rows l0+ct-3 .. l0+ct (4 rows) at dims c*64+cd
    #define XLOAD(RX, c) { _Pragma("unroll") \
        for (int i = 0; i < 4; i++) { \
            int l = l0 + ct - 3 + i; \
            f32x4 v = {0.f, 0.f, 0.f, 0.f}; \
            if (l >= 0) v = *(const f32x4*)&x[((size_t)(bb * L_ + l)) * D_ + (c) * 64 + cd]; \
            RX[i] = v; } }
    // conv: thread = token ct x dims cd..cd+3; weights from LDS
    #define CONV(RX, c) { \
        const int dg = (c) * 64 + cd; \
        f32x4 w0 = *(const f32x4*)&cwS[dg]; \
        f32x4 w1 = *(const f32x4*)&cwS[1024 + dg]; \
        f32x4 w2 = *(const f32x4*)&cwS[2048 + dg]; \
        f32x4 w3 = *(const f32x4*)&cwS[3072 + dg]; \
        f32x4 cb = *(const f32x4*)&cwS[4096 + dg]; \
        f16 hc4[4], hx4[4]; \
        _Pragma("unroll") \
        for (int j = 0; j < 4; j++) { \
            float s0 = cb[j]; \
            s0 = fmaf(w0[j], RX[0][j], s0); \
            s0 = fmaf(w1[j], RX[1][j], s0); \
            s0 = fmaf(w2[j], RX[2][j], s0); \
            s0 = fmaf(w3[j], RX[3][j], s0); \
            hc4[j] = (f16)s0; hx4[j] = (f16)RX[3][j]; \
        } \
        *(uint2*)(chb + ct * WST + cd * 2) = *(uint2*)hc4; \
        *(uint2*)(xhb + ct * WST + cd * 2) = *(uint2*)hx4; }

    #define MFMA_PH(WTC) { \
        const bool nC = (cbase < 128); \
        const bool nX = (cbase + 32 >= 128); \
        _Pragma("unroll") \
        for (int ks = 0; ks < 2; ks++) { \
            const int cbyte = ks * 64 + q * 16; \
            const int tr = wn * 16 + r; \
            half8 a0 = *(const half8*)((WTC) + (cbase +      r) * WST + cbyte); \
            half8 a1 = *(const half8*)((WTC) + (cbase + 16 + r) * WST + cbyte); \
            half8 a2 = *(const half8*)((WTC) + (cbase + 32 + r) * WST + cbyte); \
            half8 bc = {}, bx = {}; \
            if (nC) bc = *(const half8*)(chb + tr * WST + cbyte); \
            if (nX) bx = *(const half8*)(xhb + tr * WST + cbyte); \
            acc[0] = __builtin_amdgcn_mfma_f32_16x16x32_f16( \
                a0, (cbase < 128) ? bc : bx, acc[0], 0, 0, 0); \
            acc[1] = __builtin_amdgcn_mfma_f32_16x16x32_f16( \
                a1, (cbase + 16 < 128) ? bc : bx, acc[1], 0, 0, 0); \
            acc[2] = __builtin_amdgcn_mfma_f32_16x16x32_f16( \
                a2, (cbase + 32 < 128) ? bc : bx, acc[2], 0, 0, 0); \
        } }

    // chunk: prefetch(c+1) -> conv(c) -> [lgkm0+SB+bar] -> MFMA(c)
    // -> ds_write WT(c+1) -> raw bar.  No vmcnt(0) in the loop.
    #define CHUNK(c, RXc, RSN, RXN, WTC, WTN, PF) { \
        if (PF) { WLOAD(RSN, (c) + 1); XLOAD(RXN, (c) + 1); } \
        CONV(RXc, c); \
        asm volatile("s_waitcnt lgkmcnt(0)" ::: "memory"); \
        __builtin_amdgcn_sched_barrier(0); \
        __builtin_amdgcn_s_barrier(); \
        asm volatile("" ::: "memory"); \
        MFMA_PH(WTC); \
        if (PF) { DSWT(WTN, RSN); } \
        bar_raw(); }

    // stage conv weights + bias into LDS (once)
    #pragma unroll
    for (int i = 0; i < 3; i++) {
        int idx = tid + 512 * i;
        if (idx < 1280) {
            float4 v = (idx < 1024) ? ((const float4*)conv_w)[idx]
                                    : ((const float4*)conv_b)[idx - 1024];
            ((float4*)cwS)[idx] = v;
        }
    }

    // prologue: chunk 0 staged
    WLOAD(rSa, 0);
    XLOAD(rXa, 0);
    DSWT(wt0, rSa);
    __syncthreads();

    #pragma unroll 1
    for (int cc = 0; cc < 8; cc++) {
        const int c0 = cc * 2;
        CHUNK(c0,     rXa, rSb, rXb, wt0, wt1, true);
        CHUNK(c0 + 1, rXb, rSa, rXa, wt1, wt0, (c0 + 1) < 15);
    }

    // --- epilogue: bias + activation -> sE (aliases wt0) ---
    float* sB = sE;
    float* sC = sE + 32 * 68;
    float* sU = sE + 2 * 32 * 68;
    #pragma unroll
    for (int mf = 0; mf < 3; mf++) {
        const int cb4 = cbase + mf * 16 + q * 4;
        const int seg = cb4 >> 6;          // 0=Bt 1=Ct 2=u (frag-uniform)
        const int cl = cb4 & 63;
        const float4 bb4 = (seg == 2) ? *(const float4*)&bs[cl]
                                      : *(const float4*)&bp[cb4];
        float* dst = (seg == 0) ? sB : (seg == 1 ? sC : sU);
        const int t = wn * 16 + r;
        float v0 = acc[mf][0] + bb4.x;
        float v1 = acc[mf][1] + bb4.y;
        float v2 = acc[mf][2] + bb4.z;
        float v3 = acc[mf][3] + bb4.w;
        if (seg == 0) {
            v0 = softplus_f(v0); v1 = softplus_f(v1);
            v2 = softplus_f(v2); v3 = softplus_f(v3);
        } else if (seg == 1) {
            v0 = tanh_f(v0); v1 = tanh_f(v1);
            v2 = tanh_f(v2); v3 = tanh_f(v3);
        }
        float4 vv = {v0, v1, v2, v3};
        *(float4*)&dst[t * 68 + cl] = vv;
    }
    __syncthreads();

    // --- fused combine: z = dt[n]*Bt*u, store zT/cT n-major ---
    {
        const int n = tid >> 3, tg = tid & 7;
        const float dtv = softplus_f(dt_log[n]);
        f16 hz[4], hc2[4];
        #pragma unroll
        for (int j = 0; j < 4; j++) {
            const int t = tg * 4 + j;
            hz[j] = (f16)(dtv * sB[t * 68 + n] * sU[t * 68 + n]);
            hc2[j] = (f16)sC[t * 68 + n];
        }
        size_t o = ((size_t)(bb * N_ + n)) * L_ + l0 + tg * 4;
        *(uint2*)&zT[o] = *(uint2*)hz;
        *(uint2*)&cT[o] = *(uint2*)hc2;
    }
    #undef WLOAD
    #undef DSWT
    #undef XLOAD
    #undef CONV
    #undef MFMA_PH
    #undef CHUNK
}
#undef WST

// ---------------------------------------------------------------------------
// Scan v2: 256 threads per (b,n) chain.  Thread t owns elems [16t,16t+16);
// serial 16-fma local reduce -> 64-lane shfl affine scan -> cross-wave
// stitch via LDS -> apply.  +i>>4 swizzle avoids 32-way bank conflicts.
// ---------------------------------------------------------------------------
#define ZI(i) ((i) + ((i) >> 4))
__global__ __launch_bounds__(256) void k_scan(
    const f16* __restrict__ zT, const f16* __restrict__ cT,
    const float* __restrict__ A_log, const float* __restrict__ dt_log,
    f16* __restrict__ yH)
{
    __shared__ float zs[4352];
    __shared__ float cs[4352];
    __shared__ float sA[4], sB[4];
    const int bn = blockIdx.x;
    const int n = bn & (N_ - 1);
    const int tid = threadIdx.x;
    const int lane = tid & 63, w = tid >> 6;
    const f16* zp = zT + (size_t)bn * L_;
    const f16* cp = cT + (size_t)bn * L_;

    #pragma unroll
    for (int it = 0; it < 2; it++) {
        int i = tid * 8 + it * 2048;
        uint4 rz = *(const uint4*)(zp + i);
        uint4 rc = *(const uint4*)(cp + i);
        const f16* hz = (const f16*)&rz;
        const f16* hc = (const f16*)&rc;
        #pragma unroll
        for (int k = 0; k < 8; k++) {
            zs[ZI(i + k)] = (float)hz[k];
            cs[ZI(i + k)] = (float)hc[k];
        }
    }
    __syncthreads();

    float dtv = softplus_f(dt_log[n]);
    float Av = -softplus_f(A_log[n]);
    float dec = fmaf(dtv, Av, 1.0f);

    const int base = tid * 17;           // ZI(tid*16)
    float s = 0.0f;
    #pragma unroll
    for (int j = 0; j < 16; j++) s = fmaf(dec, s, zs[base + j]);

    float d2 = dec * dec, d4 = d2 * d2, d8 = d4 * d4, d16 = d8 * d8;

    float Ag = d16, Bg = s;
    #pragma unroll
    for (int off = 1; off < 64; off <<= 1) {
        float Ap = __shfl_up(Ag, off);
        float Bp = __shfl_up(Bg, off);
        if (lane >= off) { Bg = fmaf(Ag, Bp, Bg); Ag *= Ap; }
    }
    if (lane == 63) { sA[w] = Ag; sB[w] = Bg; }
    __syncthreads();

    float Bc = 0.0f;                      // carry entering this wave
    for (int i = 0; i < w; i++) Bc = fmaf(sA[i], Bc, sB[i]);
    float Ae = __shfl_up(Ag, 1);          // exclusive within wave
    float Be = __shfl_up(Bg, 1);
    if (lane == 0) { Ae = 1.0f; Be = 0.0f; }
    float carry = fmaf(Ae, Bc, Be);       // state entering this thread

    float st = carry;
    #pragma unroll
    for (int j = 0; j < 16; j++) {
        st = fmaf(dec, st, zs[base + j]);
        zs[base + j] = cs[base + j] * st;
    }
    __syncthreads();

    f16* yp = yH + (size_t)bn * L_;
    #pragma unroll
    for (int it = 0; it < 2; it++) {
        int i = tid * 8 + it * 2048;
        f16 h[8];
        #pragma unroll
        for (int k = 0; k < 8; k++) h[k] = (f16)zs[ZI(i + k)];
        *(uint4*)&yp[i] = *(uint4*)h;
    }
}
#undef ZI

// ---------------------------------------------------------------------------
// Out GEMM: out[t][d] = y[t][:] @ Wo[:,d] + bo.  A = WoT (m=d), B = y (n=tok)
// Block 256 thr: 64 tok x 128 d, wave = 32 d x 64 tok.  Grid (256, 8).
// ---------------------------------------------------------------------------
__global__ __launch_bounds__(256) void k_out(
    const f16* __restrict__ yH, const f16* __restrict__ WoT,
    const float* __restrict__ bo, float* __restrict__ out)
{
    __shared__ __align__(16) f16 ys[64 * 72];
    const int tid = threadIdx.x;
    const int w = tid >> 6, lane = tid & 63;
    const int r = lane & 15, q = lane >> 4;
    const int T0 = blockIdx.x * 64;
    const int bb = T0 >> 12, l0 = T0 & (L_ - 1);
    const int dw = blockIdx.y * 128 + w * 32;

    // stage y transpose: [n-major global] -> ys[t][n]
    {
        const int n = tid & 63, tg = tid >> 6;
        #pragma unroll
        for (int h2 = 0; h2 < 2; h2++) {
            uint4 v = *(const uint4*)&yH[((size_t)(bb * N_ + n)) * L_ + l0 + tg * 16 + h2 * 8];
            const f16* hh = (const f16*)&v;
            #pragma unroll
            for (int j = 0; j < 8; j++)
                ys[(tg * 16 + h2 * 8 + j) * 72 + n] = hh[j];
        }
    }
    __syncthreads();

    f32x4 acc[2][4] = {};
    #pragma unroll
    for (int ks = 0; ks < 2; ks++) {
        const int kk = ks * 32 + q * 8;
        half8 af[2];
        #pragma unroll
        for (int mf = 0; mf < 2; mf++)
            af[mf] = *(const half8*)&WoT[(size_t)(dw + mf * 16 + r) * 64 + kk];
        #pragma unroll
        for (int nf = 0; nf < 4; nf++) {
            half8 bf = *(const half8*)&ys[(nf * 16 + r) * 72 + kk];
            #pragma unroll
            for (int mf = 0; mf < 2; mf++)
                acc[mf][nf] = __builtin_amdgcn_mfma_f32_16x16x32_f16(
                    af[mf], bf, acc[mf][nf], 0, 0, 0);
        }
    }

    #pragma unroll
    for (int mf = 0; mf < 2; mf++) {
        const int d = dw + mf * 16 + q * 4;
        const float4 bb4 = *(const float4*)&bo[d];
        #pragma unroll
        for (int nf = 0; nf < 4; nf++) {
            const int t = T0 + nf * 16 + r;
            float4 o = {acc[mf][nf][0] + bb4.x, acc[mf][nf][1] + bb4.y,
                        acc[mf][nf][2] + bb4.z, acc[mf][nf][3] + bb4.w};
            *(float4*)&out[(size_t)t * D_ + d] = o;
        }
    }
}

// ---------------------------------------------------------------------------
extern "C" void kernel_launch(void* const* d_in, const int* in_sizes, int n_in,
                              void* d_out, int out_size, void* d_ws, size_t ws_size,
                              hipStream_t stream) {
    const float* x      = (const float*)d_in[0];
    const float* conv_w = (const float*)d_in[1];
    const float* conv_b = (const float*)d_in[2];
    const float* Wp     = (const float*)d_in[3];
    const float* bp     = (const float*)d_in[4];
    const float* Ws     = (const float*)d_in[5];
    const float* bs     = (const float*)d_in[6];
    const float* A_log  = (const float*)d_in[7];
    const float* dt_log = (const float*)d_in[8];
    const float* Wo     = (const float*)d_in[9];
    const float* bo     = (const float*)d_in[10];
    float* out = (float*)d_out;

    char* wsp = (char*)d_ws;
    f16* WT  = (f16*)wsp;                     // 384 KB
    f16* WoT = (f16*)(wsp + 393216);          // 128 KB
    f16* zT  = (f16*)(wsp + 524288);          // 2 MB [B,N,L]
    f16* cT  = (f16*)(wsp + 2621440);         // 2 MB
    f16* yH  = (f16*)(wsp + 4718592);         // 2 MB

    k_prepw<<<dim3(128), dim3(256), 0, stream>>>(Wp, Ws, Wo, WT, WoT);
    k_frontend<<<dim3(B_ * L_ / 32), dim3(512), 0, stream>>>(
        x, conv_w, conv_b, WT, bp, bs, dt_log, zT, cT);
    k_scan<<<dim3(B_ * N_), dim3(256), 0, stream>>>(zT, cT, A_log, dt_log, yH);
    k_out<<<dim3(B_ * L_ / 64, D_ / 128), dim3(256), 0, stream>>>(yH, WoT, bo, out);
}

// Round 9
// 180.203 us; speedup vs baseline: 1.3241x; 1.3241x over previous
//
#include <hip/hip_runtime.h>

#define B_ 4
#define L_ 4096
#define D_ 1024
#define N_ 64

typedef _Float16 f16;
typedef __attribute__((ext_vector_type(8))) _Float16 half8;
typedef __attribute__((ext_vector_type(4))) float f32x4;

__device__ __forceinline__ float softplus_f(float x) {
    return fmaxf(x, 0.0f) + log1pf(__expf(-fabsf(x)));
}

__device__ __forceinline__ float tanh_f(float x) {
    float xc = fminf(fmaxf(x, -15.0f), 15.0f);
    float e = __expf(2.0f * xc);
    return (e - 1.0f) / (e + 1.0f);
}

__device__ __forceinline__ void bar_raw() {
    asm volatile("" ::: "memory");
    __builtin_amdgcn_s_barrier();
    asm volatile("" ::: "memory");
}

// async global->LDS, 16B per lane; lds base must be wave-uniform.
__device__ __forceinline__ void gld16(const void* g, void* l) {
    __builtin_amdgcn_global_load_lds(
        (const __attribute__((address_space(1))) unsigned int*)g,
        (__attribute__((address_space(3))) unsigned int*)l, 16, 0, 0);
}

// ---------------------------------------------------------------------------
// Prep: WT [192 rows][1024 dims] f16, PRE-SWIZZLED within each 128B chunk
// segment: group g of row rr stored at byte (g*16)^((rr&7)<<4).  Frontend
// stages chunks with global_load_lds (linear copy) and reads with the same
// XOR -> conflict-free without padding (m173 pattern).
// WoT [1024][64] f16 unchanged.
// ---------------------------------------------------------------------------
__global__ __launch_bounds__(256) void k_prepw(
    const float* __restrict__ Wp, const float* __restrict__ Ws,
    const float* __restrict__ Wo, f16* __restrict__ WT, f16* __restrict__ WoT)
{
    int gid = blockIdx.x * 256 + threadIdx.x;
    if (gid < 16384) {                        // Wp: [1024][128] -> rows 0-127
        int c = gid & 127, kg = gid >> 7;     // row c, k-group kg (8 f16)
        f16 h[8];
        #pragma unroll
        for (int j = 0; j < 8; j++)
            h[j] = (f16)Wp[(size_t)(kg * 8 + j) * 128 + c];
        int off = (size_t)c * 1024 + (kg >> 3) * 64 + (((kg & 7) * 8) ^ ((c & 7) << 3));
        *(uint4*)&WT[off] = *(uint4*)h;
    } else if (gid < 24576) {                 // Ws: [1024][64] -> rows 128-191
        int idx = gid - 16384;
        int c = idx & 63, kg = idx >> 6;
        int row = 128 + c;
        f16 h[8];
        #pragma unroll
        for (int j = 0; j < 8; j++)
            h[j] = (f16)Ws[(size_t)(kg * 8 + j) * 64 + c];
        int off = (size_t)row * 1024 + (kg >> 3) * 64 + (((kg & 7) * 8) ^ ((row & 7) << 3));
        *(uint4*)&WT[off] = *(uint4*)h;
    } else {                                  // Wo -> WoT [1024][64]
        int idx = gid - 24576;
        int d = idx & 1023, ng = idx >> 10;
        f16 h[8];
        #pragma unroll
        for (int j = 0; j < 8; j++)
            h[j] = (f16)Wo[(size_t)(ng * 8 + j) * D_ + d];
        *(uint4*)&WoT[(size_t)d * 64 + ng * 8] = *(uint4*)h;
    }
}

// ---------------------------------------------------------------------------
// Fused frontend v10: 32 tok/block, 512 thr / 8 waves, grid 512 = 2 blk/CU.
// WT chunk (24KB) staged via global_load_lds (ZERO staging VGPRs -> no spill,
// r8's failure mode), double-buffered, pre-swizzled source (prepw) so linear
// gload + XOR-read is bank-conflict-free.  No vmcnt(0)/drain in the loop:
// gload(c+1) issued BEFORE xload(c+1); CONV(c+1)'s counted wait on x regs
// retires the older gloads in-order; barrier (b) publishes to all waves.
// conv weights in LDS; conv buffers padded (WST=136B).  6 MFMA/chunk/wave.
// LDS 78336B -> 2 blocks/CU.  VGPR ~80 < 128 cap (launch_bounds(512,4)).
// ---------------------------------------------------------------------------
#define WST 136
__global__ __launch_bounds__(512, 4) void k_frontend(
    const float* __restrict__ x, const float* __restrict__ conv_w,
    const float* __restrict__ conv_b, const f16* __restrict__ WT,
    const float* __restrict__ bp, const float* __restrict__ bs,
    const float* __restrict__ dt_log,
    f16* __restrict__ zT, f16* __restrict__ cT)
{
    __shared__ __align__(16) char smem[78336];
    char* wt0 = smem;                     // [192][128B] chunk buf 0 (swz content)
    char* wt1 = smem + 24576;             // buf 1
    char* chb = smem + 49152;             // [32][WST] conv f16
    char* xhb = smem + 53504;             // [32][WST] raw x f16
    float* cwS = (float*)(smem + 57856);  // [5][1024] f32 (20480B)
    float* sE  = (float*)smem;            // epilogue alias [3][32][68] f32

    const int tid = threadIdx.x;
    const int w = tid >> 6, lane = tid & 63;
    const int r = lane & 15, q = lane >> 4;
    const int wc = w & 3, wn = w >> 2;
    const int T0 = blockIdx.x * 32;
    const int bb = T0 >> 12, l0 = T0 & (L_ - 1);
    const int cbase = wc * 48;
    const int ct = tid >> 4;              // conv token 0..31
    const int cd = (tid & 15) * 4;        // conv dim group (4 floats)

    f32x4 acc[3] = {};
    f32x4 rXa[4], rXb[4];

    // WT chunk stage: 1536 slots x 16B; wave w, call s covers slots
    // [w*64+512s, +64); per-lane global addr, wave-uniform LDS base.
    #define GLOADWT(BUF, c) { _Pragma("unroll") \
        for (int s = 0; s < 3; s++) { \
            int slot = tid + 512 * s; \
            int row = slot >> 3, g = slot & 7; \
            const char* gsrc = (const char*)WT + (size_t)row * 2048 + (c) * 128 + g * 16; \
            gld16(gsrc, (BUF) + (w * 64 + s * 512) * 16); \
        } }
    // x rows l0+ct-3 .. l0+ct (4 rows) at dims c*64+cd
    #define XLOAD(RX, c) { _Pragma("unroll") \
        for (int i = 0; i < 4; i++) { \
            int l = l0 + ct - 3 + i; \
            f32x4 v = {0.f, 0.f, 0.f, 0.f}; \
            if (l >= 0) v = *(const f32x4*)&x[((size_t)(bb * L_ + l)) * D_ + (c) * 64 + cd]; \
            RX[i] = v; } }
    // conv: thread = token ct x dims cd..cd+3; weights from LDS
    #define CONV(RX, c) { \
        const int dg = (c) * 64 + cd; \
        f32x4 w0 = *(const f32x4*)&cwS[dg]; \
        f32x4 w1 = *(const f32x4*)&cwS[1024 + dg]; \
        f32x4 w2 = *(const f32x4*)&cwS[2048 + dg]; \
        f32x4 w3 = *(const f32x4*)&cwS[3072 + dg]; \
        f32x4 cb = *(const f32x4*)&cwS[4096 + dg]; \
        f16 hc4[4], hx4[4]; \
        _Pragma("unroll") \
        for (int j = 0; j < 4; j++) { \
            float s0 = cb[j]; \
            s0 = fmaf(w0[j], RX[0][j], s0); \
            s0 = fmaf(w1[j], RX[1][j], s0); \
            s0 = fmaf(w2[j], RX[2][j], s0); \
            s0 = fmaf(w3[j], RX[3][j], s0); \
            hc4[j] = (f16)s0; hx4[j] = (f16)RX[3][j]; \
        } \
        *(uint2*)(chb + ct * WST + cd * 2) = *(uint2*)hc4; \
        *(uint2*)(xhb + ct * WST + cd * 2) = *(uint2*)hx4; }

    // A-read XOR matches prepw's pre-swizzle; 2 lanes/bank (free).
    #define MFMA_PH(WTC) { \
        const bool nC = (cbase < 128); \
        const bool nX = (cbase + 32 >= 128); \
        _Pragma("unroll") \
        for (int ks = 0; ks < 2; ks++) { \
            const int cbyte = ks * 64 + q * 16; \
            const int tr = wn * 16 + r; \
            const int a0r = cbase + r, a1r = cbase + 16 + r, a2r = cbase + 32 + r; \
            half8 a0 = *(const half8*)((WTC) + a0r * 128 + (cbyte ^ ((a0r & 7) << 4))); \
            half8 a1 = *(const half8*)((WTC) + a1r * 128 + (cbyte ^ ((a1r & 7) << 4))); \
            half8 a2 = *(const half8*)((WTC) + a2r * 128 + (cbyte ^ ((a2r & 7) << 4))); \
            half8 bc = {}, bx = {}; \
            if (nC) bc = *(const half8*)(chb + tr * WST + cbyte); \
            if (nX) bx = *(const half8*)(xhb + tr * WST + cbyte); \
            acc[0] = __builtin_amdgcn_mfma_f32_16x16x32_f16( \
                a0, (cbase < 128) ? bc : bx, acc[0], 0, 0, 0); \
            acc[1] = __builtin_amdgcn_mfma_f32_16x16x32_f16( \
                a1, (cbase + 16 < 128) ? bc : bx, acc[1], 0, 0, 0); \
            acc[2] = __builtin_amdgcn_mfma_f32_16x16x32_f16( \
                a2, (cbase + 32 < 128) ? bc : bx, acc[2], 0, 0, 0); \
        } }

    // chunk: gload WT(c+1) -> xload(c+1) -> conv(c) -> [lgkm0+SB+bar]
    // -> MFMA(c) -> raw bar.  No vmcnt drain anywhere.
    #define CHUNK(c, RXc, RXN, WTC, WTN, PF) { \
        if (PF) { GLOADWT(WTN, (c) + 1); XLOAD(RXN, (c) + 1); } \
        CONV(RXc, c); \
        asm volatile("s_waitcnt lgkmcnt(0)" ::: "memory"); \
        __builtin_amdgcn_sched_barrier(0); \
        __builtin_amdgcn_s_barrier(); \
        asm volatile("" ::: "memory"); \
        MFMA_PH(WTC); \
        bar_raw(); }

    // stage conv weights + bias into LDS (once)
    #pragma unroll
    for (int i = 0; i < 3; i++) {
        int idx = tid + 512 * i;
        if (idx < 1280) {
            float4 v = (idx < 1024) ? ((const float4*)conv_w)[idx]
                                    : ((const float4*)conv_b)[idx - 1024];
            ((float4*)cwS)[idx] = v;
        }
    }

    // prologue: chunk 0 staged (gload + x regs), full drain once
    GLOADWT(wt0, 0);
    XLOAD(rXa, 0);
    __syncthreads();

    #pragma unroll 1
    for (int cc = 0; cc < 8; cc++) {
        const int c0 = cc * 2;
        CHUNK(c0,     rXa, rXb, wt0, wt1, true);
        CHUNK(c0 + 1, rXb, rXa, wt1, wt0, (c0 + 1) < 15);
    }

    // --- epilogue: bias + activation -> sE (aliases wt bufs) ---
    float* sB = sE;
    float* sC = sE + 32 * 68;
    float* sU = sE + 2 * 32 * 68;
    #pragma unroll
    for (int mf = 0; mf < 3; mf++) {
        const int cb4 = cbase + mf * 16 + q * 4;
        const int seg = cb4 >> 6;          // 0=Bt 1=Ct 2=u (frag-uniform)
        const int cl = cb4 & 63;
        const float4 bb4 = (seg == 2) ? *(const float4*)&bs[cl]
                                      : *(const float4*)&bp[cb4];
        float* dst = (seg == 0) ? sB : (seg == 1 ? sC : sU);
        const int t = wn * 16 + r;
        float v0 = acc[mf][0] + bb4.x;
        float v1 = acc[mf][1] + bb4.y;
        float v2 = acc[mf][2] + bb4.z;
        float v3 = acc[mf][3] + bb4.w;
        if (seg == 0) {
            v0 = softplus_f(v0); v1 = softplus_f(v1);
            v2 = softplus_f(v2); v3 = softplus_f(v3);
        } else if (seg == 1) {
            v0 = tanh_f(v0); v1 = tanh_f(v1);
            v2 = tanh_f(v2); v3 = tanh_f(v3);
        }
        float4 vv = {v0, v1, v2, v3};
        *(float4*)&dst[t * 68 + cl] = vv;
    }
    __syncthreads();

    // --- fused combine: z = dt[n]*Bt*u, store zT/cT n-major ---
    {
        const int n = tid >> 3, tg = tid & 7;
        const float dtv = softplus_f(dt_log[n]);
        f16 hz[4], hc2[4];
        #pragma unroll
        for (int j = 0; j < 4; j++) {
            const int t = tg * 4 + j;
            hz[j] = (f16)(dtv * sB[t * 68 + n] * sU[t * 68 + n]);
            hc2[j] = (f16)sC[t * 68 + n];
        }
        size_t o = ((size_t)(bb * N_ + n)) * L_ + l0 + tg * 4;
        *(uint2*)&zT[o] = *(uint2*)hz;
        *(uint2*)&cT[o] = *(uint2*)hc2;
    }
    #undef GLOADWT
    #undef XLOAD
    #undef CONV
    #undef MFMA_PH
    #undef CHUNK
}
#undef WST

// ---------------------------------------------------------------------------
// Scan v3: 1024 threads per (b,n) chain (was 256) -> 4 waves/SIMD latency
// hiding.  Thread owns 4 elems: 4-fma local reduce -> 64-lane shfl affine
// scan -> 16-wave LDS stitch -> apply.  +i>>4 swizzle on zs/cs banks.
// ---------------------------------------------------------------------------
#define ZI(i) ((i) + ((i) >> 4))
__global__ __launch_bounds__(1024) void k_scan(
    const f16* __restrict__ zT, const f16* __restrict__ cT,
    const float* __restrict__ A_log, const float* __restrict__ dt_log,
    f16* __restrict__ yH)
{
    __shared__ float zs[4352];
    __shared__ float cs[4352];
    __shared__ float sA[16], sBv[16];
    const int bn = blockIdx.x;
    const int n = bn & (N_ - 1);
    const int tid = threadIdx.x;
    const int lane = tid & 63, w = tid >> 6;
    const f16* zp = zT + (size_t)bn * L_;
    const f16* cp = cT + (size_t)bn * L_;

    // load 4 elems/thread (8B, coalesced)
    {
        int i = tid * 4;
        uint2 rz = *(const uint2*)(zp + i);
        uint2 rc = *(const uint2*)(cp + i);
        const f16* hz = (const f16*)&rz;
        const f16* hc = (const f16*)&rc;
        #pragma unroll
        for (int k = 0; k < 4; k++) {
            zs[ZI(i + k)] = (float)hz[k];
            cs[ZI(i + k)] = (float)hc[k];
        }
    }
    __syncthreads();

    float dtv = softplus_f(dt_log[n]);
    float Av = -softplus_f(A_log[n]);
    float dec = fmaf(dtv, Av, 1.0f);

    const int base = tid * 4 + (tid >> 2);   // ZI(tid*4)
    float s = 0.0f;
    #pragma unroll
    for (int j = 0; j < 4; j++) s = fmaf(dec, s, zs[base + j]);

    float d2 = dec * dec, d4 = d2 * d2;

    float Ag = d4, Bg = s;
    #pragma unroll
    for (int off = 1; off < 64; off <<= 1) {
        float Ap = __shfl_up(Ag, off);
        float Bp = __shfl_up(Bg, off);
        if (lane >= off) { Bg = fmaf(Ag, Bp, Bg); Ag *= Ap; }
    }
    if (lane == 63) { sA[w] = Ag; sBv[w] = Bg; }
    __syncthreads();

    float Bc = 0.0f;                      // carry entering this wave
    for (int i = 0; i < w; i++) Bc = fmaf(sA[i], Bc, sBv[i]);
    float Ae = __shfl_up(Ag, 1);          // exclusive within wave
    float Be = __shfl_up(Bg, 1);
    if (lane == 0) { Ae = 1.0f; Be = 0.0f; }
    float carry = fmaf(Ae, Bc, Be);       // state entering this thread

    float st = carry;
    #pragma unroll
    for (int j = 0; j < 4; j++) {
        st = fmaf(dec, st, zs[base + j]);
        zs[base + j] = cs[base + j] * st;
    }
    __syncthreads();

    {
        int i = tid * 4;
        f16 h[4];
        #pragma unroll
        for (int k = 0; k < 4; k++) h[k] = (f16)zs[ZI(i + k)];
        *(uint2*)&yH[(size_t)bn * L_ + i] = *(uint2*)h;
    }
}
#undef ZI

// ---------------------------------------------------------------------------
// Out GEMM: out[t][d] = y[t][:] @ Wo[:,d] + bo.  A = WoT (m=d), B = y (n=tok)
// Block 256 thr: 64 tok x 128 d, wave = 32 d x 64 tok.  Grid (256, 8).
// ---------------------------------------------------------------------------
__global__ __launch_bounds__(256) void k_out(
    const f16* __restrict__ yH, const f16* __restrict__ WoT,
    const float* __restrict__ bo, float* __restrict__ out)
{
    __shared__ __align__(16) f16 ys[64 * 72];
    const int tid = threadIdx.x;
    const int w = tid >> 6, lane = tid & 63;
    const int r = lane & 15, q = lane >> 4;
    const int T0 = blockIdx.x * 64;
    const int bb = T0 >> 12, l0 = T0 & (L_ - 1);
    const int dw = blockIdx.y * 128 + w * 32;

    // stage y transpose: [n-major global] -> ys[t][n]
    {
        const int n = tid & 63, tg = tid >> 6;
        #pragma unroll
        for (int h2 = 0; h2 < 2; h2++) {
            uint4 v = *(const uint4*)&yH[((size_t)(bb * N_ + n)) * L_ + l0 + tg * 16 + h2 * 8];
            const f16* hh = (const f16*)&v;
            #pragma unroll
            for (int j = 0; j < 8; j++)
                ys[(tg * 16 + h2 * 8 + j) * 72 + n] = hh[j];
        }
    }
    __syncthreads();

    f32x4 acc[2][4] = {};
    #pragma unroll
    for (int ks = 0; ks < 2; ks++) {
        const int kk = ks * 32 + q * 8;
        half8 af[2];
        #pragma unroll
        for (int mf = 0; mf < 2; mf++)
            af[mf] = *(const half8*)&WoT[(size_t)(dw + mf * 16 + r) * 64 + kk];
        #pragma unroll
        for (int nf = 0; nf < 4; nf++) {
            half8 bf = *(const half8*)&ys[(nf * 16 + r) * 72 + kk];
            #pragma unroll
            for (int mf = 0; mf < 2; mf++)
                acc[mf][nf] = __builtin_amdgcn_mfma_f32_16x16x32_f16(
                    af[mf], bf, acc[mf][nf], 0, 0, 0);
        }
    }

    #pragma unroll
    for (int mf = 0; mf < 2; mf++) {
        const int d = dw + mf * 16 + q * 4;
        const float4 bb4 = *(const float4*)&bo[d];
        #pragma unroll
        for (int nf = 0; nf < 4; nf++) {
            const int t = T0 + nf * 16 + r;
            float4 o = {acc[mf][nf][0] + bb4.x, acc[mf][nf][1] + bb4.y,
                        acc[mf][nf][2] + bb4.z, acc[mf][nf][3] + bb4.w};
            *(float4*)&out[(size_t)t * D_ + d] = o;
        }
    }
}

// ---------------------------------------------------------------------------
extern "C" void kernel_launch(void* const* d_in, const int* in_sizes, int n_in,
                              void* d_out, int out_size, void* d_ws, size_t ws_size,
                              hipStream_t stream) {
    const float* x      = (const float*)d_in[0];
    const float* conv_w = (const float*)d_in[1];
    const float* conv_b = (const float*)d_in[2];
    const float* Wp     = (const float*)d_in[3];
    const float* bp     = (const float*)d_in[4];
    const float* Ws     = (const float*)d_in[5];
    const float* bs     = (const float*)d_in[6];
    const float* A_log  = (const float*)d_in[7];
    const float* dt_log = (const float*)d_in[8];
    const float* Wo     = (const float*)d_in[9];
    const float* bo     = (const float*)d_in[10];
    float* out = (float*)d_out;

    char* wsp = (char*)d_ws;
    f16* WT  = (f16*)wsp;                     // 384 KB (pre-swizzled)
    f16* WoT = (f16*)(wsp + 393216);          // 128 KB
    f16* zT  = (f16*)(wsp + 524288);          // 2 MB [B,N,L]
    f16* cT  = (f16*)(wsp + 2621440);         // 2 MB
    f16* yH  = (f16*)(wsp + 4718592);         // 2 MB

    k_prepw<<<dim3(128), dim3(256), 0, stream>>>(Wp, Ws, Wo, WT, WoT);
    k_frontend<<<dim3(B_ * L_ / 32), dim3(512), 0, stream>>>(
        x, conv_w, conv_b, WT, bp, bs, dt_log, zT, cT);
    k_scan<<<dim3(B_ * N_), dim3(1024), 0, stream>>>(zT, cT, A_log, dt_log, yH);
    k_out<<<dim3(B_ * L_ / 64, D_ / 128), dim3(256), 0, stream>>>(yH, WoT, bo, out);
}